// Round 3
// baseline (1536.612 us; speedup 1.0000x reference)
//
#include <hip/hip_runtime.h>
#include <hip/hip_cooperative_groups.h>
#include <hip/hip_bf16.h>

namespace cg = cooperative_groups;

// Problem constants
#define BB 64
#define II 1152
#define OO 32
#define DD 8
#define HH 16
#define BOH (BB * OO * HH)    // 32768
#define WTILE (OO * DD * HH)  // 4096 floats per i

// Decomposition
#define IC   9     // i-values per block          (NIC * IC == II)
#define NIC  128   // i-chunks
#define NBB  16    // b per block
#define NBG  4     // b-groups (NBG * NBB == BB)
#define NJB  4     // b per thread
#define WS   132   // padded LDS row stride (stride mod 32 = 4 -> balanced banks for b128)

// ---------------------------------------------------------------------------
// Fused cooperative kernel: all 3 routing iterations in one launch.
// Grid (NIC, NBG) = 512 blocks = 2 blocks/CU (co-resident with 256 thr, 21KB LDS,
// launch_bounds(256,2) caps VGPR at 256). Thread: tid = o + 32*hh + 64*bq.
// Phase p: compute partial s for this block's 9 i's (recomputing u_hat; logits
// are linear in v so vsum register state replaces a logits array), store the
// per-chunk slab, grid.sync, 128 blocks reduce+squash -> v (or final out),
// grid.sync, all blocks fold v into vsum.
// ---------------------------------------------------------------------------
__global__ __launch_bounds__(256, 2)
void fused_routing(const float* __restrict__ u, const float* __restrict__ w,
                   float* __restrict__ part, float* __restrict__ vbuf,
                   float* __restrict__ out)
{
    cg::grid_group grid = cg::this_grid();

    __shared__ float Wsh[OO * WS];        // 16.5 KB, padded rows
    __shared__ float Ush[IC * NBB * DD];  // 4.5 KB: u for all 9 i's, staged once

    const int tid   = threadIdx.x;
    const int o     = tid & 31;
    const int hh    = (tid >> 5) & 1;
    const int bq    = tid >> 6;          // 0..3
    const int bbase = blockIdx.y * NBB;
    const int i0    = blockIdx.x * IC;
    const int hofs  = hh * 8;

    // One-time u preload: Ush[(ii*NBB + bl)*DD + d], 288 float4 granules.
    for (int g = tid; g < IC * NBB * 2; g += 256) {
        const int ii = g >> 5;           // g / (NBB*2)
        const int r  = g & 31;
        const int bl = r >> 1;
        const int q4 = (r & 1) * 4;
        *(float4*)&Ush[(ii * NBB + bl) * DD + q4] =
            *(const float4*)(u + ((size_t)(bbase + bl) * II + (i0 + ii)) * DD + q4);
    }

    float vsum[NJB][8];
    #pragma unroll
    for (int jb = 0; jb < NJB; jb++)
        #pragma unroll
        for (int h2 = 0; h2 < 8; h2++) vsum[jb][h2] = 0.f;

    for (int phase = 0; phase < 3; phase++) {
        float sacc[NJB][8];
        #pragma unroll
        for (int jb = 0; jb < NJB; jb++)
            #pragma unroll
            for (int h2 = 0; h2 < 8; h2++) sacc[jb][h2] = 0.f;

        // Register-double-buffered W staging: prefetch W[i0] now.
        float4 rw[2][4];
        {
            const float* wg = w + (size_t)i0 * WTILE;
            #pragma unroll
            for (int j = 0; j < 4; j++)
                rw[0][j] = *(const float4*)(wg + (tid + j * 256) * 4);
        }

        #pragma unroll
        for (int ii = 0; ii < IC; ii++) {
            __syncthreads();             // previous iteration's LDS reads done
            #pragma unroll
            for (int j = 0; j < 4; j++) {
                const int c = tid + j * 256;
                *(float4*)&Wsh[(c >> 5) * WS + (c & 31) * 4] = rw[ii & 1][j];
            }
            if (ii + 1 < IC) {           // prefetch next W tile during compute
                const float* wg = w + (size_t)(i0 + ii + 1) * WTILE;
                #pragma unroll
                for (int j = 0; j < 4; j++)
                    rw[(ii + 1) & 1][j] = *(const float4*)(wg + (tid + j * 256) * 4);
            }
            __syncthreads();

            // u to registers (broadcast LDS reads, uniform across the 32 o-lanes)
            float us[NJB][8];
            #pragma unroll
            for (int jb = 0; jb < NJB; jb++) {
                const float* up = &Ush[(ii * NBB + bq * NJB + jb) * DD];
                float4 a = *(const float4*)up;
                float4 c = *(const float4*)(up + 4);
                us[jb][0] = a.x; us[jb][1] = a.y; us[jb][2] = a.z; us[jb][3] = a.w;
                us[jb][4] = c.x; us[jb][5] = c.y; us[jb][6] = c.z; us[jb][7] = c.w;
            }

            // u_hat[b, i, o, h-half] = sum_d u[b,i,d] * W[i,o,d,h]
            float uh[NJB][8];
            #pragma unroll
            for (int jb = 0; jb < NJB; jb++)
                #pragma unroll
                for (int h2 = 0; h2 < 8; h2++) uh[jb][h2] = 0.f;
            #pragma unroll
            for (int d = 0; d < DD; d++) {
                const float* wp = &Wsh[o * WS + d * HH + hofs];
                float4 wa = *(const float4*)wp;
                float4 wb = *(const float4*)(wp + 4);
                const float wv[8] = {wa.x, wa.y, wa.z, wa.w, wb.x, wb.y, wb.z, wb.w};
                #pragma unroll
                for (int jb = 0; jb < NJB; jb++)
                    #pragma unroll
                    for (int h2 = 0; h2 < 8; h2++)
                        uh[jb][h2] = fmaf(us[jb][d], wv[h2], uh[jb][h2]);
            }

            // coupling: softmax over o of (vsum . u_hat). Phase 0: vsum==0 -> 1/32.
            float cc[NJB];
            #pragma unroll
            for (int jb = 0; jb < NJB; jb++) {
                float lg = 0.f;
                #pragma unroll
                for (int h2 = 0; h2 < 8; h2++)
                    lg = fmaf(vsum[jb][h2], uh[jb][h2], lg);
                lg += __shfl_xor(lg, 32, 64);          // combine h-halves
                const float e = __expf(lg);            // |lg| small -> no max-sub
                float se = e;
                #pragma unroll
                for (int off = 16; off >= 1; off >>= 1)
                    se += __shfl_xor(se, off, 64);
                cc[jb] = __fdividef(e, se);
            }

            #pragma unroll
            for (int jb = 0; jb < NJB; jb++)
                #pragma unroll
                for (int h2 = 0; h2 < 8; h2++)
                    sacc[jb][h2] = fmaf(cc[jb], uh[jb][h2], sacc[jb][h2]);
        }

        // store this block's partial slab (fully-covered contiguous lines)
        #pragma unroll
        for (int jb = 0; jb < NJB; jb++) {
            const int b = bbase + bq * NJB + jb;
            float* p = part + ((size_t)blockIdx.x * BB + b) * (OO * HH) + o * HH + hofs;
            *(float4*)p       = make_float4(sacc[jb][0], sacc[jb][1], sacc[jb][2], sacc[jb][3]);
            *(float4*)(p + 4) = make_float4(sacc[jb][4], sacc[jb][5], sacc[jb][6], sacc[jb][7]);
        }
        __threadfence();
        grid.sync();

        // reduce + squash: 128 blocks (y==0), one thread per (b,o,h)
        if (blockIdx.y == 0) {
            const int t = blockIdx.x * 256 + tid;      // 0..BOH-1
            float acc = 0.f;
            #pragma unroll 8
            for (int ic = 0; ic < NIC; ic++)
                acc += part[(size_t)ic * BOH + t];
            float sq = acc * acc;
            #pragma unroll
            for (int off = 8; off >= 1; off >>= 1)
                sq += __shfl_xor(sq, off, 16);         // sum over h-group of 16
            const float scale = (sq / (1.f + sq)) * rsqrtf(sq + 1e-8f);
            if (phase < 2) vbuf[t] = acc * scale;
            else           out[t]  = acc * scale;      // final output
            __threadfence();
        }
        if (phase == 2) return;
        grid.sync();

        // fold v into vsum (logits linear in v)
        #pragma unroll
        for (int jb = 0; jb < NJB; jb++) {
            const int b = bbase + bq * NJB + jb;
            const float* p = vbuf + (b * OO + o) * HH + hofs;
            float4 a = *(const float4*)p;
            float4 c = *(const float4*)(p + 4);
            vsum[jb][0] += a.x; vsum[jb][1] += a.y; vsum[jb][2] += a.z; vsum[jb][3] += a.w;
            vsum[jb][4] += c.x; vsum[jb][5] += c.y; vsum[jb][6] += c.z; vsum[jb][7] += c.w;
        }
    }
}

// ---------------------------------------------------------------------------
// Fallback path (R2): separate pass / reduce kernels, used if the cooperative
// launch is unavailable or ws is too small.
// ---------------------------------------------------------------------------
template<int PASS, bool ATOMIC>
__global__ __launch_bounds__(256, 2)
void pass_kernel(const float* __restrict__ u, const float* __restrict__ w,
                 const float* __restrict__ pv0, const float* __restrict__ pv1,
                 float* __restrict__ out)
{
    __shared__ float Wsh[OO * WS];
    __shared__ float Ush[NBB * DD];

    const int tid   = threadIdx.x;
    const int o     = tid & 31;
    const int hh    = (tid >> 5) & 1;
    const int bq    = tid >> 6;
    const int bbase = blockIdx.y * NBB;
    const int i0    = blockIdx.x * IC;
    const int hofs  = hh * 8;

    float vsum[NJB][8];
    if (PASS >= 1) {
        #pragma unroll
        for (int jb = 0; jb < NJB; jb++) {
            const int b = bbase + bq * NJB + jb;
            const float* p = pv0 + ((b * OO + o) * HH + hofs);
            float4 a = *(const float4*)p;
            float4 c = *(const float4*)(p + 4);
            vsum[jb][0] = a.x; vsum[jb][1] = a.y; vsum[jb][2] = a.z; vsum[jb][3] = a.w;
            vsum[jb][4] = c.x; vsum[jb][5] = c.y; vsum[jb][6] = c.z; vsum[jb][7] = c.w;
            if (PASS == 2) {
                const float* q = pv1 + ((b * OO + o) * HH + hofs);
                float4 a2 = *(const float4*)q;
                float4 c2 = *(const float4*)(q + 4);
                vsum[jb][0] += a2.x; vsum[jb][1] += a2.y; vsum[jb][2] += a2.z; vsum[jb][3] += a2.w;
                vsum[jb][4] += c2.x; vsum[jb][5] += c2.y; vsum[jb][6] += c2.z; vsum[jb][7] += c2.w;
            }
        }
    }

    float sacc[NJB][8];
    #pragma unroll
    for (int jb = 0; jb < NJB; jb++)
        #pragma unroll
        for (int h2 = 0; h2 < 8; h2++) sacc[jb][h2] = 0.f;

    for (int ii = 0; ii < IC; ii++) {
        const int i = i0 + ii;
        __syncthreads();
        {
            const float* wg = w + (size_t)i * WTILE;
            #pragma unroll
            for (int j = 0; j < 4; j++) {
                const int c    = tid + j * 256;
                float4 val     = *(const float4*)(wg + c * 4);
                *(float4*)&Wsh[(c >> 5) * WS + (c & 31) * 4] = val;
            }
            if (tid < NBB * 2) {
                const int bl = tid >> 1, q4 = (tid & 1) * 4;
                *(float4*)&Ush[bl * DD + q4] =
                    *(const float4*)(u + ((size_t)(bbase + bl) * II + i) * DD + q4);
            }
        }
        __syncthreads();

        float us[NJB][8];
        #pragma unroll
        for (int jb = 0; jb < NJB; jb++) {
            const int bl = bq * NJB + jb;
            float4 a = *(const float4*)&Ush[bl * DD];
            float4 c = *(const float4*)&Ush[bl * DD + 4];
            us[jb][0] = a.x; us[jb][1] = a.y; us[jb][2] = a.z; us[jb][3] = a.w;
            us[jb][4] = c.x; us[jb][5] = c.y; us[jb][6] = c.z; us[jb][7] = c.w;
        }

        float uh[NJB][8];
        #pragma unroll
        for (int jb = 0; jb < NJB; jb++)
            #pragma unroll
            for (int h2 = 0; h2 < 8; h2++) uh[jb][h2] = 0.f;
        #pragma unroll
        for (int d = 0; d < DD; d++) {
            const float* wp = &Wsh[o * WS + d * HH + hofs];
            float4 wa = *(const float4*)wp;
            float4 wb = *(const float4*)(wp + 4);
            const float wv[8] = {wa.x, wa.y, wa.z, wa.w, wb.x, wb.y, wb.z, wb.w};
            #pragma unroll
            for (int jb = 0; jb < NJB; jb++)
                #pragma unroll
                for (int h2 = 0; h2 < 8; h2++)
                    uh[jb][h2] = fmaf(us[jb][d], wv[h2], uh[jb][h2]);
        }

        float cc[NJB];
        if (PASS == 0) {
            #pragma unroll
            for (int jb = 0; jb < NJB; jb++) cc[jb] = 1.0f / 32.0f;
        } else {
            #pragma unroll
            for (int jb = 0; jb < NJB; jb++) {
                float lg = 0.f;
                #pragma unroll
                for (int h2 = 0; h2 < 8; h2++)
                    lg = fmaf(vsum[jb][h2], uh[jb][h2], lg);
                lg += __shfl_xor(lg, 32, 64);
                const float e = __expf(lg);
                float se = e;
                #pragma unroll
                for (int off = 16; off >= 1; off >>= 1)
                    se += __shfl_xor(se, off, 64);
                cc[jb] = __fdividef(e, se);
            }
        }

        #pragma unroll
        for (int jb = 0; jb < NJB; jb++)
            #pragma unroll
            for (int h2 = 0; h2 < 8; h2++)
                sacc[jb][h2] = fmaf(cc[jb], uh[jb][h2], sacc[jb][h2]);
    }

    #pragma unroll
    for (int jb = 0; jb < NJB; jb++) {
        const int b = bbase + bq * NJB + jb;
        if (ATOMIC) {
            float* p = out + ((b * OO + o) * HH + hofs);
            #pragma unroll
            for (int h2 = 0; h2 < 8; h2++) atomicAdd(p + h2, sacc[jb][h2]);
        } else {
            float* p = out + ((size_t)blockIdx.x * BB + b) * (OO * HH) + o * HH + hofs;
            *(float4*)p       = make_float4(sacc[jb][0], sacc[jb][1], sacc[jb][2], sacc[jb][3]);
            *(float4*)(p + 4) = make_float4(sacc[jb][4], sacc[jb][5], sacc[jb][6], sacc[jb][7]);
        }
    }
}

__global__ __launch_bounds__(256)
void reduce_squash_kernel(const float* __restrict__ part, float* __restrict__ v)
{
    const int t = blockIdx.x * blockDim.x + threadIdx.x;
    float acc = 0.f;
    #pragma unroll 8
    for (int ic = 0; ic < NIC; ic++)
        acc += part[(size_t)ic * BOH + t];
    float sq = acc * acc;
    #pragma unroll
    for (int off = 8; off >= 1; off >>= 1)
        sq += __shfl_xor(sq, off, 16);
    const float scale = (sq / (1.f + sq)) * rsqrtf(sq + 1e-8f);
    v[t] = acc * scale;
}

__global__ __launch_bounds__(256)
void squash_kernel(const float* __restrict__ s, float* __restrict__ v)
{
    const int t = blockIdx.x * blockDim.x + threadIdx.x;
    if (t >= BB * OO) return;
    const float4* sp = (const float4*)(s + t * HH);
    float4 a = sp[0], b = sp[1], c = sp[2], d = sp[3];
    float sq = a.x*a.x + a.y*a.y + a.z*a.z + a.w*a.w
             + b.x*b.x + b.y*b.y + b.z*b.z + b.w*b.w
             + c.x*c.x + c.y*c.y + c.z*c.z + c.w*c.w
             + d.x*d.x + d.y*d.y + d.z*d.z + d.w*d.w;
    const float scale = (sq / (1.f + sq)) * rsqrtf(sq + 1e-8f);
    a.x *= scale; a.y *= scale; a.z *= scale; a.w *= scale;
    b.x *= scale; b.y *= scale; b.z *= scale; b.w *= scale;
    c.x *= scale; c.y *= scale; c.z *= scale; c.w *= scale;
    d.x *= scale; d.y *= scale; d.z *= scale; d.w *= scale;
    float4* vp = (float4*)(v + t * HH);
    vp[0] = a; vp[1] = b; vp[2] = c; vp[3] = d;
}

extern "C" void kernel_launch(void* const* d_in, const int* in_sizes, int n_in,
                              void* d_out, int out_size, void* d_ws, size_t ws_size,
                              hipStream_t stream)
{
    (void)in_sizes; (void)n_in; (void)out_size;
    const float* u = (const float*)d_in[0];
    const float* w = (const float*)d_in[1];
    float* out = (float*)d_out;

    const size_t need = ((size_t)NIC * BOH + 2 * BOH) * sizeof(float);  // ~16.3 MB
    const dim3 grid(NIC, NBG), blk(256);

    if (ws_size >= need) {
        float* part = (float*)d_ws;                 // NIC x BOH partial s
        float* vbuf = part + (size_t)NIC * BOH;
        float* v1   = vbuf + BOH;

        // Preferred: single cooperative launch (5 grid syncs, no kernel gaps).
        void* args[] = { (void*)&u, (void*)&w, (void*)&part, (void*)&vbuf, (void*)&out };
        hipError_t e = hipLaunchCooperativeKernel((const void*)fused_routing,
                                                  grid, blk, args, 0, stream);
        if (e == hipSuccess) return;
        (void)hipGetLastError();                    // clear sticky error, fall back

        const int rblocks = BOH / 256;
        pass_kernel<0, false><<<grid, blk, 0, stream>>>(u, w, nullptr, nullptr, part);
        reduce_squash_kernel<<<rblocks, 256, 0, stream>>>(part, vbuf);
        pass_kernel<1, false><<<grid, blk, 0, stream>>>(u, w, vbuf, nullptr, part);
        reduce_squash_kernel<<<rblocks, 256, 0, stream>>>(part, v1);
        pass_kernel<2, false><<<grid, blk, 0, stream>>>(u, w, vbuf, v1, part);
        reduce_squash_kernel<<<rblocks, 256, 0, stream>>>(part, out);
    } else {
        // Tiny-ws fallback: atomic path.
        float* s0 = (float*)d_ws;
        float* s1 = s0 + BOH;
        float* v0 = s1 + BOH;
        float* v1 = v0 + BOH;
        hipMemsetAsync(d_ws, 0, 2 * BOH * sizeof(float), stream);
        hipMemsetAsync(d_out, 0, BOH * sizeof(float), stream);
        const int sq_blocks = (BB * OO + 255) / 256;

        pass_kernel<0, true><<<grid, blk, 0, stream>>>(u, w, nullptr, nullptr, s0);
        squash_kernel<<<sq_blocks, 256, 0, stream>>>(s0, v0);
        pass_kernel<1, true><<<grid, blk, 0, stream>>>(u, w, v0, nullptr, s1);
        squash_kernel<<<sq_blocks, 256, 0, stream>>>(s1, v1);
        pass_kernel<2, true><<<grid, blk, 0, stream>>>(u, w, v0, v1, out);
        squash_kernel<<<sq_blocks, 256, 0, stream>>>(out, out);
    }
}

// Round 4
// 602.884 us; speedup vs baseline: 2.5488x; 2.5488x over previous
//
#include <hip/hip_runtime.h>
#include <hip/hip_cooperative_groups.h>
#include <hip/hip_bf16.h>

namespace cg = cooperative_groups;

// Problem constants
#define BB 64
#define II 1152
#define OO 32
#define DD 8
#define HH 16
#define BOH (BB * OO * HH)    // 32768
#define WTILE (OO * DD * HH)  // 4096 floats per i

// Shared decomposition
#define IC   9     // i-values per block          (NIC * IC == II)
#define NIC  128   // i-chunks
#define WS   132   // padded LDS row stride (breaks 32-way b128 conflicts)

// Fused-kernel decomposition: 512 threads, 32 b per block, grid (128,2) = 256 blocks
#define FNBB 32
#define FNJB 4

// Fallback decomposition (R2-proven)
#define NBB  16
#define NBG  4
#define NJB  4

// ---------------------------------------------------------------------------
// Fused cooperative kernel: all 3 routing iterations in one launch.
// 256 blocks x 512 threads = 1 block/CU (co-resident; LDS 43 KB, VGPR <= 256
// forced by flat WGS 512 -> no spills, unlike R3's 128-cap).
// tid = o + 32*hh + 64*bq  (o: out-capsule lane, hh: h-half, bq in 0..7).
// Per phase: recompute u_hat per i (W staged via LDS double-buffer, global
// loads overlapped with compute), coupling = softmax_o(vsum . u_hat) done
// in-wave, s accumulated in registers, per-chunk slab stored; grid.sync;
// 128-thread groups reduce 128 chunks + squash -> v; grid.sync; fold v into
// register vsum (logits are linear in v, so no logits array exists at all).
// ---------------------------------------------------------------------------
__global__ __launch_bounds__(512)
void fused_routing(const float* __restrict__ u, const float* __restrict__ w,
                   float* __restrict__ part, float* __restrict__ vbuf,
                   float* __restrict__ out)
{
    cg::grid_group grid = cg::this_grid();

    __shared__ float Wsh[2][OO * WS];       // 2 x 16.5 KB double buffer
    __shared__ float Ush[IC * FNBB * DD];   // 9 KB: u for all 9 i's, staged once

    const int tid   = threadIdx.x;
    const int o     = tid & 31;
    const int hh    = (tid >> 5) & 1;
    const int bq    = tid >> 6;            // 0..7
    const int bbase = blockIdx.y * FNBB;   // 0 or 32
    const int i0    = blockIdx.x * IC;
    const int hofs  = hh * 8;

    // One-time u preload: 576 float4 granules.
    for (int g = tid; g < IC * FNBB * 2; g += 512) {
        const int ii = g >> 6;             // granule / (FNBB*2)
        const int r  = g & 63;
        const int bl = r >> 1;
        const int q4 = (r & 1) * 4;
        *(float4*)&Ush[(ii * FNBB + bl) * DD + q4] =
            *(const float4*)(u + ((size_t)(bbase + bl) * II + (i0 + ii)) * DD + q4);
    }

    float vsum[FNJB][8];
    #pragma unroll
    for (int jb = 0; jb < FNJB; jb++)
        #pragma unroll
        for (int h2 = 0; h2 < 8; h2++) vsum[jb][h2] = 0.f;

    for (int phase = 0; phase < 3; phase++) {
        float sacc[FNJB][8];
        #pragma unroll
        for (int jb = 0; jb < FNJB; jb++)
            #pragma unroll
            for (int h2 = 0; h2 < 8; h2++) sacc[jb][h2] = 0.f;

        // Prologue: stage W[i0] into buffer 0 (1024 chunks, 2/thread).
        {
            const float* wg = w + (size_t)i0 * WTILE;
            #pragma unroll
            for (int j = 0; j < 2; j++) {
                const int c = tid + j * 512;
                float4 v4 = *(const float4*)(wg + c * 4);
                *(float4*)&Wsh[0][(c >> 5) * WS + (c & 31) * 4] = v4;
            }
        }
        __syncthreads();

        for (int ii = 0; ii < IC; ii++) {
            const float* wcur = Wsh[ii & 1];
            const bool pf = (ii + 1 < IC);
            float4 t0, t1;                  // W[i+1] in flight during compute
            if (pf) {
                const float* wg = w + (size_t)(i0 + ii + 1) * WTILE;
                t0 = *(const float4*)(wg + tid * 4);
                t1 = *(const float4*)(wg + (tid + 512) * 4);
            }

            // u to registers (broadcast LDS reads; bq is wave-uniform)
            float us[FNJB][8];
            #pragma unroll
            for (int jb = 0; jb < FNJB; jb++) {
                const float* up = &Ush[(ii * FNBB + bq * FNJB + jb) * DD];
                float4 a = *(const float4*)up;
                float4 c = *(const float4*)(up + 4);
                us[jb][0] = a.x; us[jb][1] = a.y; us[jb][2] = a.z; us[jb][3] = a.w;
                us[jb][4] = c.x; us[jb][5] = c.y; us[jb][6] = c.z; us[jb][7] = c.w;
            }

            // u_hat[b, i, o, h-half] = sum_d u[b,i,d] * W[i,o,d,h]
            float uh[FNJB][8];
            #pragma unroll
            for (int jb = 0; jb < FNJB; jb++)
                #pragma unroll
                for (int h2 = 0; h2 < 8; h2++) uh[jb][h2] = 0.f;
            #pragma unroll
            for (int d = 0; d < DD; d++) {
                const float* wp = &wcur[o * WS + d * HH + hofs];
                float4 wa = *(const float4*)wp;
                float4 wb = *(const float4*)(wp + 4);
                const float wv[8] = {wa.x, wa.y, wa.z, wa.w, wb.x, wb.y, wb.z, wb.w};
                #pragma unroll
                for (int jb = 0; jb < FNJB; jb++)
                    #pragma unroll
                    for (int h2 = 0; h2 < 8; h2++)
                        uh[jb][h2] = fmaf(us[jb][d], wv[h2], uh[jb][h2]);
            }

            // coupling: softmax over o of (vsum . u_hat); phase 0: vsum==0 -> 1/32
            float cc[FNJB];
            #pragma unroll
            for (int jb = 0; jb < FNJB; jb++) {
                float lg = 0.f;
                #pragma unroll
                for (int h2 = 0; h2 < 8; h2++)
                    lg = fmaf(vsum[jb][h2], uh[jb][h2], lg);
                lg += __shfl_xor(lg, 32, 64);          // combine h-halves
                const float e = __expf(lg);            // |lg| small -> no max-sub
                float se = e;
                #pragma unroll
                for (int off = 16; off >= 1; off >>= 1)
                    se += __shfl_xor(se, off, 64);
                cc[jb] = __fdividef(e, se);
            }

            #pragma unroll
            for (int jb = 0; jb < FNJB; jb++)
                #pragma unroll
                for (int h2 = 0; h2 < 8; h2++)
                    sacc[jb][h2] = fmaf(cc[jb], uh[jb][h2], sacc[jb][h2]);

            // write W[i+1] into the other buffer (vmcnt wait lands here, after compute)
            if (pf) {
                float* wn = Wsh[(ii + 1) & 1];
                const int c0 = tid, c1 = tid + 512;
                *(float4*)&wn[(c0 >> 5) * WS + (c0 & 31) * 4] = t0;
                *(float4*)&wn[(c1 >> 5) * WS + (c1 & 31) * 4] = t1;
            }
            __syncthreads();
        }

        // store this block's partial slab (fully-covered contiguous lines)
        #pragma unroll
        for (int jb = 0; jb < FNJB; jb++) {
            const int b = bbase + bq * FNJB + jb;
            float* p = part + ((size_t)blockIdx.x * BB + b) * (OO * HH) + o * HH + hofs;
            *(float4*)p       = make_float4(sacc[jb][0], sacc[jb][1], sacc[jb][2], sacc[jb][3]);
            *(float4*)(p + 4) = make_float4(sacc[jb][4], sacc[jb][5], sacc[jb][6], sacc[jb][7]);
        }
        __threadfence();
        grid.sync();

        // reduce + squash: 256 flat blocks x 128 threads = BOH threads
        {
            const int bid = blockIdx.y * NIC + blockIdx.x;   // 0..255
            if (tid < 128) {
                const int t = bid * 128 + tid;               // 0..BOH-1
                float acc = 0.f;
                #pragma unroll 8
                for (int ic = 0; ic < NIC; ic++)
                    acc += part[(size_t)ic * BOH + t];
                float sq = acc * acc;
                #pragma unroll
                for (int off = 8; off >= 1; off >>= 1)
                    sq += __shfl_xor(sq, off, 16);           // sum over h-group of 16
                const float scale = (sq / (1.f + sq)) * rsqrtf(sq + 1e-8f);
                if (phase < 2) vbuf[t] = acc * scale;
                else           out[t]  = acc * scale;
            }
        }
        if (phase == 2) return;
        __threadfence();
        grid.sync();

        // fold v into vsum (logits are linear in v)
        #pragma unroll
        for (int jb = 0; jb < FNJB; jb++) {
            const int b = bbase + bq * FNJB + jb;
            const float* p = vbuf + (b * OO + o) * HH + hofs;
            float4 a = *(const float4*)p;
            float4 c = *(const float4*)(p + 4);
            vsum[jb][0] += a.x; vsum[jb][1] += a.y; vsum[jb][2] += a.z; vsum[jb][3] += a.w;
            vsum[jb][4] += c.x; vsum[jb][5] += c.y; vsum[jb][6] += c.z; vsum[jb][7] += c.w;
        }
    }
}

// ---------------------------------------------------------------------------
// Fallback path (R2-proven, 163 us): separate pass / reduce kernels.
// ---------------------------------------------------------------------------
template<int PASS, bool ATOMIC>
__global__ __launch_bounds__(256, 2)
void pass_kernel(const float* __restrict__ u, const float* __restrict__ w,
                 const float* __restrict__ pv0, const float* __restrict__ pv1,
                 float* __restrict__ out)
{
    __shared__ float Wsh[OO * WS];
    __shared__ float Ush[NBB * DD];

    const int tid   = threadIdx.x;
    const int o     = tid & 31;
    const int hh    = (tid >> 5) & 1;
    const int bq    = tid >> 6;
    const int bbase = blockIdx.y * NBB;
    const int i0    = blockIdx.x * IC;
    const int hofs  = hh * 8;

    float vsum[NJB][8];
    if (PASS >= 1) {
        #pragma unroll
        for (int jb = 0; jb < NJB; jb++) {
            const int b = bbase + bq * NJB + jb;
            const float* p = pv0 + ((b * OO + o) * HH + hofs);
            float4 a = *(const float4*)p;
            float4 c = *(const float4*)(p + 4);
            vsum[jb][0] = a.x; vsum[jb][1] = a.y; vsum[jb][2] = a.z; vsum[jb][3] = a.w;
            vsum[jb][4] = c.x; vsum[jb][5] = c.y; vsum[jb][6] = c.z; vsum[jb][7] = c.w;
            if (PASS == 2) {
                const float* q = pv1 + ((b * OO + o) * HH + hofs);
                float4 a2 = *(const float4*)q;
                float4 c2 = *(const float4*)(q + 4);
                vsum[jb][0] += a2.x; vsum[jb][1] += a2.y; vsum[jb][2] += a2.z; vsum[jb][3] += a2.w;
                vsum[jb][4] += c2.x; vsum[jb][5] += c2.y; vsum[jb][6] += c2.z; vsum[jb][7] += c2.w;
            }
        }
    }

    float sacc[NJB][8];
    #pragma unroll
    for (int jb = 0; jb < NJB; jb++)
        #pragma unroll
        for (int h2 = 0; h2 < 8; h2++) sacc[jb][h2] = 0.f;

    for (int ii = 0; ii < IC; ii++) {
        const int i = i0 + ii;
        __syncthreads();
        {
            const float* wg = w + (size_t)i * WTILE;
            #pragma unroll
            for (int j = 0; j < 4; j++) {
                const int c = tid + j * 256;
                float4 val  = *(const float4*)(wg + c * 4);
                *(float4*)&Wsh[(c >> 5) * WS + (c & 31) * 4] = val;
            }
            if (tid < NBB * 2) {
                const int bl = tid >> 1, q4 = (tid & 1) * 4;
                *(float4*)&Ush[bl * DD + q4] =
                    *(const float4*)(u + ((size_t)(bbase + bl) * II + i) * DD + q4);
            }
        }
        __syncthreads();

        float us[NJB][8];
        #pragma unroll
        for (int jb = 0; jb < NJB; jb++) {
            const int bl = bq * NJB + jb;
            float4 a = *(const float4*)&Ush[bl * DD];
            float4 c = *(const float4*)&Ush[bl * DD + 4];
            us[jb][0] = a.x; us[jb][1] = a.y; us[jb][2] = a.z; us[jb][3] = a.w;
            us[jb][4] = c.x; us[jb][5] = c.y; us[jb][6] = c.z; us[jb][7] = c.w;
        }

        float uh[NJB][8];
        #pragma unroll
        for (int jb = 0; jb < NJB; jb++)
            #pragma unroll
            for (int h2 = 0; h2 < 8; h2++) uh[jb][h2] = 0.f;
        #pragma unroll
        for (int d = 0; d < DD; d++) {
            const float* wp = &Wsh[o * WS + d * HH + hofs];
            float4 wa = *(const float4*)wp;
            float4 wb = *(const float4*)(wp + 4);
            const float wv[8] = {wa.x, wa.y, wa.z, wa.w, wb.x, wb.y, wb.z, wb.w};
            #pragma unroll
            for (int jb = 0; jb < NJB; jb++)
                #pragma unroll
                for (int h2 = 0; h2 < 8; h2++)
                    uh[jb][h2] = fmaf(us[jb][d], wv[h2], uh[jb][h2]);
        }

        float cc[NJB];
        if (PASS == 0) {
            #pragma unroll
            for (int jb = 0; jb < NJB; jb++) cc[jb] = 1.0f / 32.0f;
        } else {
            #pragma unroll
            for (int jb = 0; jb < NJB; jb++) {
                float lg = 0.f;
                #pragma unroll
                for (int h2 = 0; h2 < 8; h2++)
                    lg = fmaf(vsum[jb][h2], uh[jb][h2], lg);
                lg += __shfl_xor(lg, 32, 64);
                const float e = __expf(lg);
                float se = e;
                #pragma unroll
                for (int off = 16; off >= 1; off >>= 1)
                    se += __shfl_xor(se, off, 64);
                cc[jb] = __fdividef(e, se);
            }
        }

        #pragma unroll
        for (int jb = 0; jb < NJB; jb++)
            #pragma unroll
            for (int h2 = 0; h2 < 8; h2++)
                sacc[jb][h2] = fmaf(cc[jb], uh[jb][h2], sacc[jb][h2]);
    }

    #pragma unroll
    for (int jb = 0; jb < NJB; jb++) {
        const int b = bbase + bq * NJB + jb;
        if (ATOMIC) {
            float* p = out + ((b * OO + o) * HH + hofs);
            #pragma unroll
            for (int h2 = 0; h2 < 8; h2++) atomicAdd(p + h2, sacc[jb][h2]);
        } else {
            float* p = out + ((size_t)blockIdx.x * BB + b) * (OO * HH) + o * HH + hofs;
            *(float4*)p       = make_float4(sacc[jb][0], sacc[jb][1], sacc[jb][2], sacc[jb][3]);
            *(float4*)(p + 4) = make_float4(sacc[jb][4], sacc[jb][5], sacc[jb][6], sacc[jb][7]);
        }
    }
}

__global__ __launch_bounds__(256)
void reduce_squash_kernel(const float* __restrict__ part, float* __restrict__ v)
{
    const int t = blockIdx.x * blockDim.x + threadIdx.x;
    float acc = 0.f;
    #pragma unroll 8
    for (int ic = 0; ic < NIC; ic++)
        acc += part[(size_t)ic * BOH + t];
    float sq = acc * acc;
    #pragma unroll
    for (int off = 8; off >= 1; off >>= 1)
        sq += __shfl_xor(sq, off, 16);
    const float scale = (sq / (1.f + sq)) * rsqrtf(sq + 1e-8f);
    v[t] = acc * scale;
}

__global__ __launch_bounds__(256)
void squash_kernel(const float* __restrict__ s, float* __restrict__ v)
{
    const int t = blockIdx.x * blockDim.x + threadIdx.x;
    if (t >= BB * OO) return;
    const float4* sp = (const float4*)(s + t * HH);
    float4 a = sp[0], b = sp[1], c = sp[2], d = sp[3];
    float sq = a.x*a.x + a.y*a.y + a.z*a.z + a.w*a.w
             + b.x*b.x + b.y*b.y + b.z*b.z + b.w*b.w
             + c.x*c.x + c.y*c.y + c.z*c.z + c.w*c.w
             + d.x*d.x + d.y*d.y + d.z*d.z + d.w*d.w;
    const float scale = (sq / (1.f + sq)) * rsqrtf(sq + 1e-8f);
    a.x *= scale; a.y *= scale; a.z *= scale; a.w *= scale;
    b.x *= scale; b.y *= scale; b.z *= scale; b.w *= scale;
    c.x *= scale; c.y *= scale; c.z *= scale; c.w *= scale;
    d.x *= scale; d.y *= scale; d.z *= scale; d.w *= scale;
    float4* vp = (float4*)(v + t * HH);
    vp[0] = a; vp[1] = b; vp[2] = c; vp[3] = d;
}

extern "C" void kernel_launch(void* const* d_in, const int* in_sizes, int n_in,
                              void* d_out, int out_size, void* d_ws, size_t ws_size,
                              hipStream_t stream)
{
    (void)in_sizes; (void)n_in; (void)out_size;
    const float* u = (const float*)d_in[0];
    const float* w = (const float*)d_in[1];
    float* out = (float*)d_out;

    const size_t need = ((size_t)NIC * BOH + 2 * BOH) * sizeof(float);  // ~16.3 MB

    if (ws_size >= need) {
        float* part = (float*)d_ws;                 // NIC x BOH partial s
        float* vbuf = part + (size_t)NIC * BOH;
        float* v1   = vbuf + BOH;

        // Preferred: single cooperative launch (5 grid syncs, no kernel gaps).
        void* args[] = { (void*)&u, (void*)&w, (void*)&part, (void*)&vbuf, (void*)&out };
        hipError_t e = hipLaunchCooperativeKernel((const void*)fused_routing,
                                                  dim3(NIC, 2), dim3(512),
                                                  args, 0, stream);
        if (e == hipSuccess) return;
        (void)hipGetLastError();                    // clear sticky error, fall back

        const dim3 grid(NIC, NBG), blk(256);
        const int rblocks = BOH / 256;
        pass_kernel<0, false><<<grid, blk, 0, stream>>>(u, w, nullptr, nullptr, part);
        reduce_squash_kernel<<<rblocks, 256, 0, stream>>>(part, vbuf);
        pass_kernel<1, false><<<grid, blk, 0, stream>>>(u, w, vbuf, nullptr, part);
        reduce_squash_kernel<<<rblocks, 256, 0, stream>>>(part, v1);
        pass_kernel<2, false><<<grid, blk, 0, stream>>>(u, w, vbuf, v1, part);
        reduce_squash_kernel<<<rblocks, 256, 0, stream>>>(part, out);
    } else {
        // Tiny-ws fallback: atomic path.
        float* s0 = (float*)d_ws;
        float* s1 = s0 + BOH;
        float* v0 = s1 + BOH;
        float* v1 = v0 + BOH;
        hipMemsetAsync(d_ws, 0, 2 * BOH * sizeof(float), stream);
        hipMemsetAsync(d_out, 0, BOH * sizeof(float), stream);
        const dim3 grid(NIC, NBG), blk(256);
        const int sq_blocks = (BB * OO + 255) / 256;

        pass_kernel<0, true><<<grid, blk, 0, stream>>>(u, w, nullptr, nullptr, s0);
        squash_kernel<<<sq_blocks, 256, 0, stream>>>(s0, v0);
        pass_kernel<1, true><<<grid, blk, 0, stream>>>(u, w, v0, nullptr, s1);
        squash_kernel<<<sq_blocks, 256, 0, stream>>>(s1, v1);
        pass_kernel<2, true><<<grid, blk, 0, stream>>>(u, w, v0, v1, out);
        squash_kernel<<<sq_blocks, 256, 0, stream>>>(out, out);
    }
}

// Round 5
// 142.707 us; speedup vs baseline: 10.7676x; 4.2246x over previous
//
#include <hip/hip_runtime.h>
#include <hip/hip_bf16.h>

// Problem constants
#define BB 64
#define II 1152
#define OO 32
#define DD 8
#define HH 16
#define BOH (BB * OO * HH)    // 32768
#define WTILE (OO * DD * HH)  // 4096 floats per i

// Decomposition
#define IC   9     // i-values per block          (NIC * IC == II)
#define NIC  128   // i-chunks
#define NBB  16    // b per block
#define NBG  4     // b-groups (NBG * NBB == BB)
#define NJB  4     // b per thread
#define WS   132   // padded LDS row stride (breaks 32-way b128 conflicts)

// ---------------------------------------------------------------------------
// Pass kernel: one routing iteration. 512 blocks (grid NIC x NBG) x 256 thr =
// 2 blocks/CU. tid = o + 32*hh + 64*bq. Logits are linear in v, so vsum
// (= v0 [+ v1]) replaces any logits array; PASS 0 has uniform coupling 1/32.
// W is staged through a 2-buffer LDS pipeline: W[i+1] global loads issue
// before the compute on W[i], LDS writes land after compute, one barrier per
// iteration -> global latency overlapped (R4-proven inner loop; grid.sync was
// R4's poison, not this pipeline). u for all 9 i's staged once up front.
// ---------------------------------------------------------------------------
template<int PASS, bool ATOMIC>
__global__ __launch_bounds__(256)
void pass_kernel(const float* __restrict__ u, const float* __restrict__ w,
                 const float* __restrict__ pv0, const float* __restrict__ pv1,
                 float* __restrict__ out)
{
    __shared__ float Wsh[2][OO * WS];     // 2 x 16.5 KB double buffer
    __shared__ float Ush[IC * NBB * DD];  // 4.5 KB: u for all 9 i's

    const int tid   = threadIdx.x;
    const int o     = tid & 31;
    const int hh    = (tid >> 5) & 1;
    const int bq    = tid >> 6;           // 0..3
    const int bbase = blockIdx.y * NBB;
    const int i0    = blockIdx.x * IC;
    const int hofs  = hh * 8;

    // One-time u preload: 288 float4 granules by 256 threads.
    for (int g = tid; g < IC * NBB * 2; g += 256) {
        const int ii = g >> 5;            // g / (NBB*2)
        const int r  = g & 31;
        const int bl = r >> 1;
        const int q4 = (r & 1) * 4;
        *(float4*)&Ush[(ii * NBB + bl) * DD + q4] =
            *(const float4*)(u + ((size_t)(bbase + bl) * II + (i0 + ii)) * DD + q4);
    }

    // vsum = sum of previous v's (constant over i); loads overlap W prologue.
    float vsum[NJB][8];
    if (PASS >= 1) {
        #pragma unroll
        for (int jb = 0; jb < NJB; jb++) {
            const int b = bbase + bq * NJB + jb;
            const float* p = pv0 + ((b * OO + o) * HH + hofs);
            float4 a = *(const float4*)p;
            float4 c = *(const float4*)(p + 4);
            vsum[jb][0] = a.x; vsum[jb][1] = a.y; vsum[jb][2] = a.z; vsum[jb][3] = a.w;
            vsum[jb][4] = c.x; vsum[jb][5] = c.y; vsum[jb][6] = c.z; vsum[jb][7] = c.w;
            if (PASS == 2) {
                const float* q = pv1 + ((b * OO + o) * HH + hofs);
                float4 a2 = *(const float4*)q;
                float4 c2 = *(const float4*)(q + 4);
                vsum[jb][0] += a2.x; vsum[jb][1] += a2.y; vsum[jb][2] += a2.z; vsum[jb][3] += a2.w;
                vsum[jb][4] += c2.x; vsum[jb][5] += c2.y; vsum[jb][6] += c2.z; vsum[jb][7] += c2.w;
            }
        }
    }

    float sacc[NJB][8];
    #pragma unroll
    for (int jb = 0; jb < NJB; jb++)
        #pragma unroll
        for (int h2 = 0; h2 < 8; h2++) sacc[jb][h2] = 0.f;

    // Prologue: stage W[i0] into buffer 0 (1024 float4 chunks, 4/thread).
    {
        const float* wg = w + (size_t)i0 * WTILE;
        #pragma unroll
        for (int j = 0; j < 4; j++) {
            const int c = tid + j * 256;
            float4 v4 = *(const float4*)(wg + c * 4);
            *(float4*)&Wsh[0][(c >> 5) * WS + (c & 31) * 4] = v4;
        }
    }
    __syncthreads();

    for (int ii = 0; ii < IC; ii++) {
        const float* wcur = Wsh[ii & 1];
        const bool pf = (ii + 1 < IC);
        float4 t0, t1, t2, t3;            // W[i+1] in flight during compute
        if (pf) {
            const float* wg = w + (size_t)(i0 + ii + 1) * WTILE;
            t0 = *(const float4*)(wg + (tid      ) * 4);
            t1 = *(const float4*)(wg + (tid + 256) * 4);
            t2 = *(const float4*)(wg + (tid + 512) * 4);
            t3 = *(const float4*)(wg + (tid + 768) * 4);
        }

        // u to registers (broadcast LDS reads; bq wave-uniform)
        float us[NJB][8];
        #pragma unroll
        for (int jb = 0; jb < NJB; jb++) {
            const float* up = &Ush[(ii * NBB + bq * NJB + jb) * DD];
            float4 a = *(const float4*)up;
            float4 c = *(const float4*)(up + 4);
            us[jb][0] = a.x; us[jb][1] = a.y; us[jb][2] = a.z; us[jb][3] = a.w;
            us[jb][4] = c.x; us[jb][5] = c.y; us[jb][6] = c.z; us[jb][7] = c.w;
        }

        // u_hat[b, i, o, h-half] = sum_d u[b,i,d] * W[i,o,d,h]
        float uh[NJB][8];
        #pragma unroll
        for (int jb = 0; jb < NJB; jb++)
            #pragma unroll
            for (int h2 = 0; h2 < 8; h2++) uh[jb][h2] = 0.f;
        #pragma unroll
        for (int d = 0; d < DD; d++) {
            const float* wp = &wcur[o * WS + d * HH + hofs];
            float4 wa = *(const float4*)wp;
            float4 wb = *(const float4*)(wp + 4);
            const float wv[8] = {wa.x, wa.y, wa.z, wa.w, wb.x, wb.y, wb.z, wb.w};
            #pragma unroll
            for (int jb = 0; jb < NJB; jb++)
                #pragma unroll
                for (int h2 = 0; h2 < 8; h2++)
                    uh[jb][h2] = fmaf(us[jb][d], wv[h2], uh[jb][h2]);
        }

        // coupling: softmax over o of (vsum . u_hat); PASS 0 -> uniform 1/32
        float cc[NJB];
        if (PASS == 0) {
            #pragma unroll
            for (int jb = 0; jb < NJB; jb++) cc[jb] = 1.0f / 32.0f;
        } else {
            #pragma unroll
            for (int jb = 0; jb < NJB; jb++) {
                float lg = 0.f;
                #pragma unroll
                for (int h2 = 0; h2 < 8; h2++)
                    lg = fmaf(vsum[jb][h2], uh[jb][h2], lg);
                lg += __shfl_xor(lg, 32, 64);          // combine h-halves
                const float e = __expf(lg);            // |lg| small -> no max-sub
                float se = e;
                #pragma unroll
                for (int off = 16; off >= 1; off >>= 1)
                    se += __shfl_xor(se, off, 64);     // sum over the 32 o-lanes
                cc[jb] = __fdividef(e, se);
            }
        }

        #pragma unroll
        for (int jb = 0; jb < NJB; jb++)
            #pragma unroll
            for (int h2 = 0; h2 < 8; h2++)
                sacc[jb][h2] = fmaf(cc[jb], uh[jb][h2], sacc[jb][h2]);

        // write W[i+1] into the other buffer (vmcnt wait lands here, post-compute)
        if (pf) {
            float* wn = Wsh[(ii + 1) & 1];
            const int c0 = tid, c1 = tid + 256, c2 = tid + 512, c3 = tid + 768;
            *(float4*)&wn[(c0 >> 5) * WS + (c0 & 31) * 4] = t0;
            *(float4*)&wn[(c1 >> 5) * WS + (c1 & 31) * 4] = t1;
            *(float4*)&wn[(c2 >> 5) * WS + (c2 & 31) * 4] = t2;
            *(float4*)&wn[(c3 >> 5) * WS + (c3 & 31) * 4] = t3;
        }
        __syncthreads();
    }

    // emit partial s
    #pragma unroll
    for (int jb = 0; jb < NJB; jb++) {
        const int b = bbase + bq * NJB + jb;
        if (ATOMIC) {
            float* p = out + ((b * OO + o) * HH + hofs);
            #pragma unroll
            for (int h2 = 0; h2 < 8; h2++) atomicAdd(p + h2, sacc[jb][h2]);
        } else {
            // per-chunk slab: fully-covered contiguous lines
            float* p = out + ((size_t)blockIdx.x * BB + b) * (OO * HH) + o * HH + hofs;
            *(float4*)p       = make_float4(sacc[jb][0], sacc[jb][1], sacc[jb][2], sacc[jb][3]);
            *(float4*)(p + 4) = make_float4(sacc[jb][4], sacc[jb][5], sacc[jb][6], sacc[jb][7]);
        }
    }
}

// Fused reduce-over-chunks + squash. BOH threads; t -> (b,o,h), h = t & 15.
// Deep unroll -> 16 loads in flight per thread (latency-bound read of part).
__global__ __launch_bounds__(256)
void reduce_squash_kernel(const float* __restrict__ part, float* __restrict__ v)
{
    const int t = blockIdx.x * blockDim.x + threadIdx.x;   // 0..BOH-1
    float acc = 0.f;
    #pragma unroll 16
    for (int ic = 0; ic < NIC; ic++)
        acc += part[(size_t)ic * BOH + t];
    float sq = acc * acc;
    #pragma unroll
    for (int off = 8; off >= 1; off >>= 1)
        sq += __shfl_xor(sq, off, 16);                     // sum over h-group of 16
    const float scale = (sq / (1.f + sq)) * rsqrtf(sq + 1e-8f);
    v[t] = acc * scale;
}

// Standalone squash for the atomic tiny-ws fallback.
__global__ __launch_bounds__(256)
void squash_kernel(const float* __restrict__ s, float* __restrict__ v)
{
    const int t = blockIdx.x * blockDim.x + threadIdx.x;
    if (t >= BB * OO) return;
    const float4* sp = (const float4*)(s + t * HH);
    float4 a = sp[0], b = sp[1], c = sp[2], d = sp[3];
    float sq = a.x*a.x + a.y*a.y + a.z*a.z + a.w*a.w
             + b.x*b.x + b.y*b.y + b.z*b.z + b.w*b.w
             + c.x*c.x + c.y*c.y + c.z*c.z + c.w*c.w
             + d.x*d.x + d.y*d.y + d.z*d.z + d.w*d.w;
    const float scale = (sq / (1.f + sq)) * rsqrtf(sq + 1e-8f);
    a.x *= scale; a.y *= scale; a.z *= scale; a.w *= scale;
    b.x *= scale; b.y *= scale; b.z *= scale; b.w *= scale;
    c.x *= scale; c.y *= scale; c.z *= scale; c.w *= scale;
    d.x *= scale; d.y *= scale; d.z *= scale; d.w *= scale;
    float4* vp = (float4*)(v + t * HH);
    vp[0] = a; vp[1] = b; vp[2] = c; vp[3] = d;
}

extern "C" void kernel_launch(void* const* d_in, const int* in_sizes, int n_in,
                              void* d_out, int out_size, void* d_ws, size_t ws_size,
                              hipStream_t stream)
{
    (void)in_sizes; (void)n_in; (void)out_size;
    const float* u = (const float*)d_in[0];
    const float* w = (const float*)d_in[1];
    float* out = (float*)d_out;

    const size_t need = ((size_t)NIC * BOH + 2 * BOH) * sizeof(float);  // ~16.3 MB
    const dim3 grid(NIC, NBG), blk(256);

    if (ws_size >= need) {
        // 6 dispatches; kernel boundaries are the (cheap) grid barrier.
        // Cooperative grid.sync measured ~80-100 us/sync on this platform (R4) — do not use.
        float* part = (float*)d_ws;                 // NIC x BOH partial s
        float* v0   = part + (size_t)NIC * BOH;
        float* v1   = v0 + BOH;
        const int rblocks = BOH / 256;              // 128

        pass_kernel<0, false><<<grid, blk, 0, stream>>>(u, w, nullptr, nullptr, part);
        reduce_squash_kernel<<<rblocks, 256, 0, stream>>>(part, v0);
        pass_kernel<1, false><<<grid, blk, 0, stream>>>(u, w, v0, nullptr, part);
        reduce_squash_kernel<<<rblocks, 256, 0, stream>>>(part, v1);
        pass_kernel<2, false><<<grid, blk, 0, stream>>>(u, w, v0, v1, part);
        reduce_squash_kernel<<<rblocks, 256, 0, stream>>>(part, out);
    } else {
        // Tiny-ws fallback: atomic path.
        float* s0 = (float*)d_ws;
        float* s1 = s0 + BOH;
        float* v0 = s1 + BOH;
        float* v1 = v0 + BOH;
        hipMemsetAsync(d_ws, 0, 2 * BOH * sizeof(float), stream);
        hipMemsetAsync(d_out, 0, BOH * sizeof(float), stream);
        const int sq_blocks = (BB * OO + 255) / 256;

        pass_kernel<0, true><<<grid, blk, 0, stream>>>(u, w, nullptr, nullptr, s0);
        squash_kernel<<<sq_blocks, 256, 0, stream>>>(s0, v0);
        pass_kernel<1, true><<<grid, blk, 0, stream>>>(u, w, v0, nullptr, s1);
        squash_kernel<<<sq_blocks, 256, 0, stream>>>(s1, v1);
        pass_kernel<2, true><<<grid, blk, 0, stream>>>(u, w, v0, v1, out);
        squash_kernel<<<sq_blocks, 256, 0, stream>>>(out, out);
    }
}